// Round 5
// baseline (1783.941 us; speedup 1.0000x reference)
//
#include <hip/hip_runtime.h>

// LOBRM fused recurrence on gfx950 — fp16 hi/lo split-precision MFMA, R5.
// R5 = R4 numerics (hi+lo for every matmul input; independent hh/hl/lh
// accumulator chains; MFMA-vol on wave 0; pointer-advance gather) with a
// restructured launch: 128 blocks x 512 threads, each block runs TWO
// independent 16-row tiles (waves 0-3 = tile 0, waves 4-7 = tile 1, disjoint
// LDS). This puts 2 waves on every active SIMD so one tile's issue fills the
// other tile's LDS/MFMA latency stalls (R4 was 1 wave/SIMD, ~50% stall).
// Also: mask-sum reduction replaced by __ballot (data msk half is abs()'d in
// setup, so sum>0 <=> any>0).

typedef __attribute__((ext_vector_type(8))) _Float16 half8;  // 8 fp16 = 4 VGPRs
typedef __attribute__((ext_vector_type(4))) float floatx4;   // MFMA C/D

#define MFMA(a, b, c) __builtin_amdgcn_mfma_f32_16x16x32_f16((a), (b), (c), 0, 0, 0)

__device__ __forceinline__ float tanhf_fast(float x) {
    float e = __builtin_exp2f(x * 2.8853900817779268f);  // e^{2x}
    return 1.0f - 2.0f / (e + 1.0f);                     // inf-safe: ->1 / -1
}
__device__ __forceinline__ float sigmoidf_fast(float x) {
    float e = __builtin_exp2f(x * -1.4426950408889634f); // e^{-x}
    return 1.0f / (1.0f + e);
}

struct W2 { half8 h, l; };

__global__ __launch_bounds__(512, 2)
void lobrm_fused(const float* __restrict__ data,   // (4096,64,100)
                 const int*   __restrict__ tsteps, // (4096,64)
                 const float* __restrict__ Wu1, const float* __restrict__ bu1,
                 const float* __restrict__ Wu2, const float* __restrict__ bu2,
                 const float* __restrict__ Wr1, const float* __restrict__ br1,
                 const float* __restrict__ Wr2, const float* __restrict__ br2,
                 const float* __restrict__ Wn1, const float* __restrict__ bn1,
                 const float* __restrict__ Wn2, const float* __restrict__ bn2,
                 const float* __restrict__ Wo1, const float* __restrict__ bo1,
                 const float* __restrict__ Wo2, const float* __restrict__ bo2,
                 const float* __restrict__ Wd,  const float* __restrict__ bd,
                 float* __restrict__ out)
{
    // Per-tile fp16 hi/lo activation buffers (x2 tiles). Row strides 72/136
    // halfs: 16B-aligned rows for half8 (b128) access.
    __shared__ __align__(16) _Float16 sYh [2][16 * 72],  sYl [2][16 * 72];
    __shared__ __align__(16) _Float16 sTh [2][16 * 72],  sTl [2][16 * 72];
    __shared__ __align__(16) _Float16 sHuh[2][16 * 72],  sHul[2][16 * 72];
    __shared__ __align__(16) _Float16 sHrh[2][16 * 72],  sHrl[2][16 * 72];
    __shared__ __align__(16) _Float16 sHnh[2][16 * 72],  sHnl[2][16 * 72];
    __shared__ __align__(16) _Float16 sYCh[2][16 * 136], sYCl[2][16 * 136];
    __shared__ __align__(16) _Float16 sCCh[2][16 * 136], sCCl[2][16 * 136];
    __shared__ float    sVol[2][16 * 132];   // vol per row per step
    __shared__ unsigned sFlg[2][16];         // apply = upd && m, per row

    const int tid   = threadIdx.x;
    const int lane  = tid & 63;
    const int wv    = tid >> 6;          // 0..7
    const int tl    = wv >> 2;           // tile 0/1
    const int w4    = wv & 3;            // wave-within-tile = N-slice
    const int col16 = lane & 15;
    const int quad  = lane >> 4;
    const int ncol  = w4 * 16 + col16;   // output column 0..63
    const int rowBase = blockIdx.x * 32 + tl * 16;  // tile's first batch row

    _Float16* pYh  = sYh[tl];  _Float16* pYl  = sYl[tl];
    _Float16* pTh  = sTh[tl];  _Float16* pTl  = sTl[tl];
    _Float16* pHuh = sHuh[tl]; _Float16* pHul = sHul[tl];
    _Float16* pHrh = sHrh[tl]; _Float16* pHrl = sHrl[tl];
    _Float16* pHnh = sHnh[tl]; _Float16* pHnl = sHnl[tl];
    _Float16* pYCh = sYCh[tl]; _Float16* pYCl = sYCl[tl];
    _Float16* pCCh = sCCh[tl]; _Float16* pCCl = sCCl[tl];
    float*    pVol = sVol[tl];
    unsigned* pFlg = sFlg[tl];

    // ---- prologue: zero state + pad regions (pads must stay 0 forever) ----
    for (int x = tid; x < 2 * 16 * 72; x += 512) {
        sYh[0][x] = (_Float16)0.f; sYl[0][x] = (_Float16)0.f;
    }
    for (int x = tid; x < 2 * 16 * 136; x += 512) {
        sYCh[0][x] = (_Float16)0.f; sYCl[0][x] = (_Float16)0.f;
        sCCh[0][x] = (_Float16)0.f; sCCl[0][x] = (_Float16)0.f;
    }
    const float bdv = bd[0];

    // ---- weight hi/lo B-fragments (this wave's 16-col slice) ----
    // B-frag for 16x16x32: lane holds B[k = kb*32 + quad*8 + j][n = ncol]
    auto loadW = [&](const float* W, int Kw, int kb) -> W2 {
        W2 f;
#pragma unroll
        for (int j = 0; j < 8; ++j) {
            int k = kb * 32 + quad * 8 + j;
            float v = (k < Kw) ? W[k * 64 + ncol] : 0.0f;
            _Float16 h = (_Float16)v;
            f.h[j] = h;
            f.l[j] = (_Float16)(v - (float)h);
        }
        return f;
    };
    W2 wO1[2], wO2[2], wU2[2], wR2[2], wN2[2], wU1[4], wR1[4], wN1[4];
#pragma unroll
    for (int kb = 0; kb < 2; ++kb) {
        wO1[kb] = loadW(Wo1, 64, kb);
        wO2[kb] = loadW(Wo2, 64, kb);
        wU2[kb] = loadW(Wu2, 64, kb);
        wR2[kb] = loadW(Wr2, 64, kb);
        wN2[kb] = loadW(Wn2, 64, kb);
    }
#pragma unroll
    for (int kb = 0; kb < 4; ++kb) {
        wU1[kb] = loadW(Wu1, 114, kb);
        wR1[kb] = loadW(Wr1, 114, kb);
        wN1[kb] = loadW(Wn1, 114, kb);
    }
    // vol B-frag (wave 0 of each tile): column 0 = Wd, cols 1..15 = 0. hi+lo.
    W2 vwd[2];
#pragma unroll
    for (int kb = 0; kb < 2; ++kb)
#pragma unroll
        for (int j = 0; j < 8; ++j) {
            int k = kb * 32 + quad * 8 + j;
            float v = (col16 == 0) ? Wd[k] : 0.0f;
            _Float16 h = (_Float16)v;
            vwd[kb].h[j] = h;
            vwd[kb].l[j] = (_Float16)(v - (float)h);
        }
    const float bo1v = bo1[ncol], bo2v = bo2[ncol];
    const float bu1v = bu1[ncol], bu2v = bu2[ncol];
    const float br1v = br1[ncol], br2v = br2[ncol];
    const float bn1v = bn1[ncol], bn2v = bn2[ncol];

    // ---- presence masks (dedup == reference's presence): wave w4 owns
    // rows 4*w4..4*w4+3 of its tile for feat loading ----
    unsigned long long mLo[4], mHi[4];
    const float* dPtr[4];
#pragma unroll
    for (int r4 = 0; r4 < 4; ++r4) {
        int b = rowBase + 4 * w4 + r4;
        int v = tsteps[b * 64 + lane];
        unsigned long long lo = (v < 64) ? (1ull << v) : 0ull;
        unsigned long long hi = (v >= 64) ? (1ull << (v - 64)) : 0ull;
#pragma unroll
        for (int st = 1; st < 64; st <<= 1) {
            lo |= __shfl_xor(lo, st);
            hi |= __shfl_xor(hi, st);
        }
        mLo[r4] = lo; mHi[r4] = hi;
        dPtr[r4] = data + (size_t)b * 6400;
    }
    __syncthreads();

    floatx4 pc = {0.f, 0.f, 0.f, 0.f};   // fp32 state, C-layout slice
    const floatx4 z = {0.f, 0.f, 0.f, 0.f};

    const int aOff  = col16 * 72 + quad * 8;   // stride-72 A-frag base
    const int aOffH = col16 * 136 + quad * 8;  // stride-136 A-frag base

    for (int i = 0; i < 128; ++i) {
        // ---- A) issue feat global loads for this step (indep of chain) ----
        bool hasU[4];
        float fv[4], mv[4];
#pragma unroll
        for (int r4 = 0; r4 < 4; ++r4) {
            unsigned long long mm = (i < 64) ? (mLo[r4] >> i) : (mHi[r4] >> (i - 64));
            hasU[r4] = (mm & 1ull) != 0ull;
            fv[r4] = 0.f; mv[r4] = 0.f;
            if (hasU[r4]) {
                const float* dp = dPtr[r4];
                dPtr[r4] = dp + 100;
                if (lane < 50) { fv[r4] = dp[lane]; mv[r4] = dp[50 + lane]; }
            }
        }

        // ---- mm1: t = tanh(y @ Wo1 + bo1); wave 0: vol = y @ Wd + bd ----
        {
            half8 a0h = *(const half8*)&pYh[aOff];
            half8 a0l = *(const half8*)&pYl[aOff];
            half8 a1h = *(const half8*)&pYh[aOff + 32];
            half8 a1l = *(const half8*)&pYl[aOff + 32];
            floatx4 hh = MFMA(a1h, wO1[1].h, MFMA(a0h, wO1[0].h, z));
            floatx4 hl = MFMA(a1h, wO1[1].l, MFMA(a0h, wO1[0].l, z));
            floatx4 lh = MFMA(a1l, wO1[1].h, MFMA(a0l, wO1[0].h, z));
            if (w4 == 0) {
                floatx4 vhh = MFMA(a1h, vwd[1].h, MFMA(a0h, vwd[0].h, z));
                floatx4 vhl = MFMA(a1h, vwd[1].l, MFMA(a0h, vwd[0].l, z));
                floatx4 vlh = MFMA(a1l, vwd[1].h, MFMA(a0l, vwd[0].h, z));
                floatx4 v = vhh + (vhl + vlh);
                if (col16 == 0) {
#pragma unroll
                    for (int r = 0; r < 4; ++r)
                        pVol[(quad * 4 + r) * 132 + i] = v[r] + bdv;
                }
            }
            floatx4 acc = hh + (hl + lh);
#pragma unroll
            for (int r = 0; r < 4; ++r) {
                float t = tanhf_fast(acc[r] + bo1v);
                _Float16 h = (_Float16)t;
                int idx = (quad * 4 + r) * 72 + ncol;
                pTh[idx] = h;
                pTl[idx] = (_Float16)(t - (float)h);
            }
        }
        __syncthreads();                                   // B1

        // ---- mm2: y1 = y + t @ Wo2 + bo2 ----
        floatx4 y1;
        {
            half8 t0h = *(const half8*)&pTh[aOff];
            half8 t0l = *(const half8*)&pTl[aOff];
            half8 t1h = *(const half8*)&pTh[aOff + 32];
            half8 t1l = *(const half8*)&pTl[aOff + 32];
            floatx4 hh = MFMA(t1h, wO2[1].h, MFMA(t0h, wO2[0].h, z));
            floatx4 hl = MFMA(t1h, wO2[1].l, MFMA(t0h, wO2[0].l, z));
            floatx4 lh = MFMA(t1l, wO2[1].h, MFMA(t0l, wO2[0].h, z));
            floatx4 acc = hh + (hl + lh);
#pragma unroll
            for (int r = 0; r < 4; ++r) {
                y1[r] = pc[r] + acc[r] + bo2v;
                _Float16 h = (_Float16)y1[r];
                int idx = (quad * 4 + r) * 136 + ncol;
                pYCh[idx] = h;
                pYCl[idx] = (_Float16)(y1[r] - (float)h);
            }
        }

        // ---- C) feat commit (hi+lo) + flags (ballot replaces reduce) ----
#pragma unroll
        for (int r4 = 0; r4 < 4; ++r4) {
            int row = 4 * w4 + r4;
            if (hasU[r4]) {
                if (lane < 50) {
                    float f = fv[r4];
                    _Float16 h = (_Float16)f;
                    _Float16 l = (_Float16)(f - (float)h);
                    int idx = row * 136 + 64 + lane;
                    pYCh[idx] = h; pYCl[idx] = l;
                    pCCh[idx] = h; pCCl[idx] = l;
                }
                // msk half of data is abs()'d in setup: sum>0 <=> any>0
                unsigned long long bal = __ballot(mv[r4] > 0.f);
                if (lane == 0) pFlg[row] = bal ? 1u : 0u;
            } else if (lane == 0) {
                pFlg[row] = 0u;
            }
        }
        __syncthreads();                                   // B2

        // ---- mm3: hu = tanh(yc@Wu1+bu1), hr = tanh(yc@Wr1+br1), K=128 ----
        {
            half8 ah0 = *(const half8*)&pYCh[aOffH];
            half8 ah1 = *(const half8*)&pYCh[aOffH + 32];
            half8 ah2 = *(const half8*)&pYCh[aOffH + 64];
            half8 ah3 = *(const half8*)&pYCh[aOffH + 96];
            half8 al0 = *(const half8*)&pYCl[aOffH];
            half8 al1 = *(const half8*)&pYCl[aOffH + 32];
            half8 al2 = *(const half8*)&pYCl[aOffH + 64];
            half8 al3 = *(const half8*)&pYCl[aOffH + 96];
            floatx4 uhh = MFMA(ah3, wU1[3].h, MFMA(ah2, wU1[2].h,
                          MFMA(ah1, wU1[1].h, MFMA(ah0, wU1[0].h, z))));
            floatx4 uhl = MFMA(ah3, wU1[3].l, MFMA(ah2, wU1[2].l,
                          MFMA(ah1, wU1[1].l, MFMA(ah0, wU1[0].l, z))));
            floatx4 ulh = MFMA(al3, wU1[3].h, MFMA(al2, wU1[2].h,
                          MFMA(al1, wU1[1].h, MFMA(al0, wU1[0].h, z))));
            floatx4 rhh = MFMA(ah3, wR1[3].h, MFMA(ah2, wR1[2].h,
                          MFMA(ah1, wR1[1].h, MFMA(ah0, wR1[0].h, z))));
            floatx4 rhl = MFMA(ah3, wR1[3].l, MFMA(ah2, wR1[2].l,
                          MFMA(ah1, wR1[1].l, MFMA(ah0, wR1[0].l, z))));
            floatx4 rlh = MFMA(al3, wR1[3].h, MFMA(al2, wR1[2].h,
                          MFMA(al1, wR1[1].h, MFMA(al0, wR1[0].h, z))));
            floatx4 aU = uhh + (uhl + ulh);
            floatx4 aR = rhh + (rhl + rlh);
#pragma unroll
            for (int r = 0; r < 4; ++r) {
                float tu = tanhf_fast(aU[r] + bu1v);
                float tr = tanhf_fast(aR[r] + br1v);
                int idx = (quad * 4 + r) * 72 + ncol;
                _Float16 hu = (_Float16)tu, hr = (_Float16)tr;
                pHuh[idx] = hu; pHul[idx] = (_Float16)(tu - (float)hu);
                pHrh[idx] = hr; pHrl[idx] = (_Float16)(tr - (float)hr);
            }
        }
        __syncthreads();                                   // B3

        // ---- mm4: u = sig(hu@Wu2+bu2), r = sig(hr@Wr2+br2); cc = y1*r ----
        floatx4 uG;
        {
            half8 u0h = *(const half8*)&pHuh[aOff];
            half8 u0l = *(const half8*)&pHul[aOff];
            half8 u1h = *(const half8*)&pHuh[aOff + 32];
            half8 u1l = *(const half8*)&pHul[aOff + 32];
            floatx4 au = MFMA(u1h, wU2[1].h, MFMA(u0h, wU2[0].h, z))
                       + (MFMA(u1h, wU2[1].l, MFMA(u0h, wU2[0].l, z))
                        + MFMA(u1l, wU2[1].h, MFMA(u0l, wU2[0].h, z)));
            half8 r0h = *(const half8*)&pHrh[aOff];
            half8 r0l = *(const half8*)&pHrl[aOff];
            half8 r1h = *(const half8*)&pHrh[aOff + 32];
            half8 r1l = *(const half8*)&pHrl[aOff + 32];
            floatx4 ar = MFMA(r1h, wR2[1].h, MFMA(r0h, wR2[0].h, z))
                       + (MFMA(r1h, wR2[1].l, MFMA(r0h, wR2[0].l, z))
                        + MFMA(r1l, wR2[1].h, MFMA(r0l, wR2[0].h, z)));
#pragma unroll
            for (int r = 0; r < 4; ++r) {
                uG[r] = sigmoidf_fast(au[r] + bu2v);
                float rg = sigmoidf_fast(ar[r] + br2v);
                float cc = y1[r] * rg;
                _Float16 h = (_Float16)cc;
                int idx = (quad * 4 + r) * 136 + ncol;
                pCCh[idx] = h;
                pCCl[idx] = (_Float16)(cc - (float)h);
            }
        }
        __syncthreads();                                   // B4

        // ---- mm5: hn = tanh(cc @ Wn1 + bn1), K=128 ----
        {
            half8 ah0 = *(const half8*)&pCCh[aOffH];
            half8 ah1 = *(const half8*)&pCCh[aOffH + 32];
            half8 ah2 = *(const half8*)&pCCh[aOffH + 64];
            half8 ah3 = *(const half8*)&pCCh[aOffH + 96];
            half8 al0 = *(const half8*)&pCCl[aOffH];
            half8 al1 = *(const half8*)&pCCl[aOffH + 32];
            half8 al2 = *(const half8*)&pCCl[aOffH + 64];
            half8 al3 = *(const half8*)&pCCl[aOffH + 96];
            floatx4 nhh = MFMA(ah3, wN1[3].h, MFMA(ah2, wN1[2].h,
                          MFMA(ah1, wN1[1].h, MFMA(ah0, wN1[0].h, z))));
            floatx4 nhl = MFMA(ah3, wN1[3].l, MFMA(ah2, wN1[2].l,
                          MFMA(ah1, wN1[1].l, MFMA(ah0, wN1[0].l, z))));
            floatx4 nlh = MFMA(al3, wN1[3].h, MFMA(al2, wN1[2].h,
                          MFMA(al1, wN1[1].h, MFMA(al0, wN1[0].h, z))));
            floatx4 aN = nhh + (nhl + nlh);
#pragma unroll
            for (int r = 0; r < 4; ++r) {
                float t = tanhf_fast(aN[r] + bn1v);
                _Float16 h = (_Float16)t;
                int idx = (quad * 4 + r) * 72 + ncol;
                pHnh[idx] = h;
                pHnl[idx] = (_Float16)(t - (float)h);
            }
        }
        __syncthreads();                                   // B5

        // ---- mm6: ns = hn@Wn2 + bn2; blend; state update ----
        {
            half8 n0h = *(const half8*)&pHnh[aOff];
            half8 n0l = *(const half8*)&pHnl[aOff];
            half8 n1h = *(const half8*)&pHnh[aOff + 32];
            half8 n1l = *(const half8*)&pHnl[aOff + 32];
            floatx4 acc = MFMA(n1h, wN2[1].h, MFMA(n0h, wN2[0].h, z))
                        + (MFMA(n1h, wN2[1].l, MFMA(n0h, wN2[0].l, z))
                         + MFMA(n1l, wN2[1].h, MFMA(n0l, wN2[0].h, z)));
#pragma unroll
            for (int r = 0; r < 4; ++r) {
                float ns = acc[r] + bn2v;
                float ny = (1.0f - uG[r]) * ns + uG[r] * y1[r];
                unsigned ap = pFlg[quad * 4 + r];          // upd && m
                float nY = ap ? ny : y1[r];                // select: NaN-safe
                pc[r] = nY;
                int rr = quad * 4 + r;
                _Float16 h = (_Float16)nY;
                pYh[rr * 72 + ncol] = h;
                pYl[rr * 72 + ncol] = (_Float16)(nY - (float)h);
            }
        }
        __syncthreads();                                   // B6
    }

    // ---- epilogue ----
#pragma unroll
    for (int r = 0; r < 4; ++r) {
        int b = rowBase + quad * 4 + r;
        out[(size_t)b * 64 + ncol] = pc[r];
    }
    float* out1 = out + (size_t)4096 * 64;
    float* out2 = out1 + (size_t)4096 * 63;
#pragma unroll
    for (int r4 = 0; r4 < 4; ++r4) {
        int row = 4 * w4 + r4;
        int b = rowBase + row;
        if (lane < 63) {
            int t0 = tsteps[b * 64 + lane];
            int t1 = tsteps[b * 64 + lane + 1];
            int iv = t0 < 126 ? t0 : 126;
            out1[(size_t)b * 63 + lane] = pVol[row * 132 + iv + 1];
            out2[(size_t)b * 63 + lane] = (float)(t1 - t0);
        }
    }
}

extern "C" void kernel_launch(void* const* d_in, const int* in_sizes, int n_in,
                              void* d_out, int out_size, void* d_ws, size_t ws_size,
                              hipStream_t stream) {
    const float* data   = (const float*)d_in[0];
    const int*   tsteps = (const int*)  d_in[1];
    const float* Wu1 = (const float*)d_in[2];  const float* bu1 = (const float*)d_in[3];
    const float* Wu2 = (const float*)d_in[4];  const float* bu2 = (const float*)d_in[5];
    const float* Wr1 = (const float*)d_in[6];  const float* br1 = (const float*)d_in[7];
    const float* Wr2 = (const float*)d_in[8];  const float* br2 = (const float*)d_in[9];
    const float* Wn1 = (const float*)d_in[10]; const float* bn1 = (const float*)d_in[11];
    const float* Wn2 = (const float*)d_in[12]; const float* bn2 = (const float*)d_in[13];
    const float* Wo1 = (const float*)d_in[14]; const float* bo1 = (const float*)d_in[15];
    const float* Wo2 = (const float*)d_in[16]; const float* bo2 = (const float*)d_in[17];
    const float* Wd  = (const float*)d_in[18]; const float* bd  = (const float*)d_in[19];
    float* out = (float*)d_out;

    lobrm_fused<<<dim3(128), dim3(512), 0, stream>>>(
        data, tsteps, Wu1, bu1, Wu2, bu2, Wr1, br1, Wr2, br2,
        Wn1, bn1, Wn2, bn2, Wo1, bo1, Wo2, bo2, Wd, bd, out);
}

// Round 6
// 1781.471 us; speedup vs baseline: 1.0014x; 1.0014x over previous
//
#include <hip/hip_runtime.h>

// LOBRM fused recurrence on gfx950 — fp16 hi/lo split-precision MFMA, R6.
// R6 = R5 with __launch_bounds__(512, 1). R5's (512,2) second arg acts with
// CUDA min-BLOCKS-per-CU semantics: 2 blocks x 8 waves = 4 waves/EU -> VGPR
// capped at 128 -> the 176-VGPR weight set spilled to scratch (FETCH 42->160MB,
// dur 565->1784us). (512,1) caps at 256 VGPRs: weights stay resident and each
// SIMD hosts 2 waves from INDEPENDENT tiles, filling latency stalls.
// 128 blocks x 512 threads; waves 0-3 = tile 0, waves 4-7 = tile 1.

typedef __attribute__((ext_vector_type(8))) _Float16 half8;  // 8 fp16 = 4 VGPRs
typedef __attribute__((ext_vector_type(4))) float floatx4;   // MFMA C/D

#define MFMA(a, b, c) __builtin_amdgcn_mfma_f32_16x16x32_f16((a), (b), (c), 0, 0, 0)

__device__ __forceinline__ float tanhf_fast(float x) {
    float e = __builtin_exp2f(x * 2.8853900817779268f);  // e^{2x}
    return 1.0f - 2.0f / (e + 1.0f);                     // inf-safe: ->1 / -1
}
__device__ __forceinline__ float sigmoidf_fast(float x) {
    float e = __builtin_exp2f(x * -1.4426950408889634f); // e^{-x}
    return 1.0f / (1.0f + e);
}

struct W2 { half8 h, l; };

__global__ __launch_bounds__(512, 1)
void lobrm_fused(const float* __restrict__ data,   // (4096,64,100)
                 const int*   __restrict__ tsteps, // (4096,64)
                 const float* __restrict__ Wu1, const float* __restrict__ bu1,
                 const float* __restrict__ Wu2, const float* __restrict__ bu2,
                 const float* __restrict__ Wr1, const float* __restrict__ br1,
                 const float* __restrict__ Wr2, const float* __restrict__ br2,
                 const float* __restrict__ Wn1, const float* __restrict__ bn1,
                 const float* __restrict__ Wn2, const float* __restrict__ bn2,
                 const float* __restrict__ Wo1, const float* __restrict__ bo1,
                 const float* __restrict__ Wo2, const float* __restrict__ bo2,
                 const float* __restrict__ Wd,  const float* __restrict__ bd,
                 float* __restrict__ out)
{
    // Per-tile fp16 hi/lo activation buffers (x2 tiles). Row strides 72/136
    // halfs: 16B-aligned rows for half8 (b128) access.
    __shared__ __align__(16) _Float16 sYh [2][16 * 72],  sYl [2][16 * 72];
    __shared__ __align__(16) _Float16 sTh [2][16 * 72],  sTl [2][16 * 72];
    __shared__ __align__(16) _Float16 sHuh[2][16 * 72],  sHul[2][16 * 72];
    __shared__ __align__(16) _Float16 sHrh[2][16 * 72],  sHrl[2][16 * 72];
    __shared__ __align__(16) _Float16 sHnh[2][16 * 72],  sHnl[2][16 * 72];
    __shared__ __align__(16) _Float16 sYCh[2][16 * 136], sYCl[2][16 * 136];
    __shared__ __align__(16) _Float16 sCCh[2][16 * 136], sCCl[2][16 * 136];
    __shared__ float    sVol[2][16 * 132];   // vol per row per step
    __shared__ unsigned sFlg[2][16];         // apply = upd && m, per row

    const int tid   = threadIdx.x;
    const int lane  = tid & 63;
    const int wv    = tid >> 6;          // 0..7
    const int tl    = wv >> 2;           // tile 0/1
    const int w4    = wv & 3;            // wave-within-tile = N-slice
    const int col16 = lane & 15;
    const int quad  = lane >> 4;
    const int ncol  = w4 * 16 + col16;   // output column 0..63
    const int rowBase = blockIdx.x * 32 + tl * 16;  // tile's first batch row

    _Float16* pYh  = sYh[tl];  _Float16* pYl  = sYl[tl];
    _Float16* pTh  = sTh[tl];  _Float16* pTl  = sTl[tl];
    _Float16* pHuh = sHuh[tl]; _Float16* pHul = sHul[tl];
    _Float16* pHrh = sHrh[tl]; _Float16* pHrl = sHrl[tl];
    _Float16* pHnh = sHnh[tl]; _Float16* pHnl = sHnl[tl];
    _Float16* pYCh = sYCh[tl]; _Float16* pYCl = sYCl[tl];
    _Float16* pCCh = sCCh[tl]; _Float16* pCCl = sCCl[tl];
    float*    pVol = sVol[tl];
    unsigned* pFlg = sFlg[tl];

    // ---- prologue: zero state + pad regions (pads must stay 0 forever) ----
    for (int x = tid; x < 2 * 16 * 72; x += 512) {
        sYh[0][x] = (_Float16)0.f; sYl[0][x] = (_Float16)0.f;
    }
    for (int x = tid; x < 2 * 16 * 136; x += 512) {
        sYCh[0][x] = (_Float16)0.f; sYCl[0][x] = (_Float16)0.f;
        sCCh[0][x] = (_Float16)0.f; sCCl[0][x] = (_Float16)0.f;
    }
    const float bdv = bd[0];

    // ---- weight hi/lo B-fragments (this wave's 16-col slice) ----
    // B-frag for 16x16x32: lane holds B[k = kb*32 + quad*8 + j][n = ncol]
    auto loadW = [&](const float* W, int Kw, int kb) -> W2 {
        W2 f;
#pragma unroll
        for (int j = 0; j < 8; ++j) {
            int k = kb * 32 + quad * 8 + j;
            float v = (k < Kw) ? W[k * 64 + ncol] : 0.0f;
            _Float16 h = (_Float16)v;
            f.h[j] = h;
            f.l[j] = (_Float16)(v - (float)h);
        }
        return f;
    };
    W2 wO1[2], wO2[2], wU2[2], wR2[2], wN2[2], wU1[4], wR1[4], wN1[4];
#pragma unroll
    for (int kb = 0; kb < 2; ++kb) {
        wO1[kb] = loadW(Wo1, 64, kb);
        wO2[kb] = loadW(Wo2, 64, kb);
        wU2[kb] = loadW(Wu2, 64, kb);
        wR2[kb] = loadW(Wr2, 64, kb);
        wN2[kb] = loadW(Wn2, 64, kb);
    }
#pragma unroll
    for (int kb = 0; kb < 4; ++kb) {
        wU1[kb] = loadW(Wu1, 114, kb);
        wR1[kb] = loadW(Wr1, 114, kb);
        wN1[kb] = loadW(Wn1, 114, kb);
    }
    // vol B-frag (wave 0 of each tile): column 0 = Wd, cols 1..15 = 0. hi+lo.
    W2 vwd[2];
#pragma unroll
    for (int kb = 0; kb < 2; ++kb)
#pragma unroll
        for (int j = 0; j < 8; ++j) {
            int k = kb * 32 + quad * 8 + j;
            float v = (col16 == 0) ? Wd[k] : 0.0f;
            _Float16 h = (_Float16)v;
            vwd[kb].h[j] = h;
            vwd[kb].l[j] = (_Float16)(v - (float)h);
        }
    const float bo1v = bo1[ncol], bo2v = bo2[ncol];
    const float bu1v = bu1[ncol], bu2v = bu2[ncol];
    const float br1v = br1[ncol], br2v = br2[ncol];
    const float bn1v = bn1[ncol], bn2v = bn2[ncol];

    // ---- presence masks (dedup == reference's presence): wave w4 owns
    // rows 4*w4..4*w4+3 of its tile for feat loading ----
    unsigned long long mLo[4], mHi[4];
    const float* dPtr[4];
#pragma unroll
    for (int r4 = 0; r4 < 4; ++r4) {
        int b = rowBase + 4 * w4 + r4;
        int v = tsteps[b * 64 + lane];
        unsigned long long lo = (v < 64) ? (1ull << v) : 0ull;
        unsigned long long hi = (v >= 64) ? (1ull << (v - 64)) : 0ull;
#pragma unroll
        for (int st = 1; st < 64; st <<= 1) {
            lo |= __shfl_xor(lo, st);
            hi |= __shfl_xor(hi, st);
        }
        mLo[r4] = lo; mHi[r4] = hi;
        dPtr[r4] = data + (size_t)b * 6400;
    }
    __syncthreads();

    floatx4 pc = {0.f, 0.f, 0.f, 0.f};   // fp32 state, C-layout slice
    const floatx4 z = {0.f, 0.f, 0.f, 0.f};

    const int aOff  = col16 * 72 + quad * 8;   // stride-72 A-frag base
    const int aOffH = col16 * 136 + quad * 8;  // stride-136 A-frag base

    for (int i = 0; i < 128; ++i) {
        // ---- A) issue feat global loads for this step (indep of chain) ----
        bool hasU[4];
        float fv[4], mv[4];
#pragma unroll
        for (int r4 = 0; r4 < 4; ++r4) {
            unsigned long long mm = (i < 64) ? (mLo[r4] >> i) : (mHi[r4] >> (i - 64));
            hasU[r4] = (mm & 1ull) != 0ull;
            fv[r4] = 0.f; mv[r4] = 0.f;
            if (hasU[r4]) {
                const float* dp = dPtr[r4];
                dPtr[r4] = dp + 100;
                if (lane < 50) { fv[r4] = dp[lane]; mv[r4] = dp[50 + lane]; }
            }
        }

        // ---- mm1: t = tanh(y @ Wo1 + bo1); wave 0: vol = y @ Wd + bd ----
        {
            half8 a0h = *(const half8*)&pYh[aOff];
            half8 a0l = *(const half8*)&pYl[aOff];
            half8 a1h = *(const half8*)&pYh[aOff + 32];
            half8 a1l = *(const half8*)&pYl[aOff + 32];
            floatx4 hh = MFMA(a1h, wO1[1].h, MFMA(a0h, wO1[0].h, z));
            floatx4 hl = MFMA(a1h, wO1[1].l, MFMA(a0h, wO1[0].l, z));
            floatx4 lh = MFMA(a1l, wO1[1].h, MFMA(a0l, wO1[0].h, z));
            if (w4 == 0) {
                floatx4 vhh = MFMA(a1h, vwd[1].h, MFMA(a0h, vwd[0].h, z));
                floatx4 vhl = MFMA(a1h, vwd[1].l, MFMA(a0h, vwd[0].l, z));
                floatx4 vlh = MFMA(a1l, vwd[1].h, MFMA(a0l, vwd[0].h, z));
                floatx4 v = vhh + (vhl + vlh);
                if (col16 == 0) {
#pragma unroll
                    for (int r = 0; r < 4; ++r)
                        pVol[(quad * 4 + r) * 132 + i] = v[r] + bdv;
                }
            }
            floatx4 acc = hh + (hl + lh);
#pragma unroll
            for (int r = 0; r < 4; ++r) {
                float t = tanhf_fast(acc[r] + bo1v);
                _Float16 h = (_Float16)t;
                int idx = (quad * 4 + r) * 72 + ncol;
                pTh[idx] = h;
                pTl[idx] = (_Float16)(t - (float)h);
            }
        }
        __syncthreads();                                   // B1

        // ---- mm2: y1 = y + t @ Wo2 + bo2 ----
        floatx4 y1;
        {
            half8 t0h = *(const half8*)&pTh[aOff];
            half8 t0l = *(const half8*)&pTl[aOff];
            half8 t1h = *(const half8*)&pTh[aOff + 32];
            half8 t1l = *(const half8*)&pTl[aOff + 32];
            floatx4 hh = MFMA(t1h, wO2[1].h, MFMA(t0h, wO2[0].h, z));
            floatx4 hl = MFMA(t1h, wO2[1].l, MFMA(t0h, wO2[0].l, z));
            floatx4 lh = MFMA(t1l, wO2[1].h, MFMA(t0l, wO2[0].h, z));
            floatx4 acc = hh + (hl + lh);
#pragma unroll
            for (int r = 0; r < 4; ++r) {
                y1[r] = pc[r] + acc[r] + bo2v;
                _Float16 h = (_Float16)y1[r];
                int idx = (quad * 4 + r) * 136 + ncol;
                pYCh[idx] = h;
                pYCl[idx] = (_Float16)(y1[r] - (float)h);
            }
        }

        // ---- C) feat commit (hi+lo) + flags (ballot replaces reduce) ----
#pragma unroll
        for (int r4 = 0; r4 < 4; ++r4) {
            int row = 4 * w4 + r4;
            if (hasU[r4]) {
                if (lane < 50) {
                    float f = fv[r4];
                    _Float16 h = (_Float16)f;
                    _Float16 l = (_Float16)(f - (float)h);
                    int idx = row * 136 + 64 + lane;
                    pYCh[idx] = h; pYCl[idx] = l;
                    pCCh[idx] = h; pCCl[idx] = l;
                }
                // msk half of data is abs()'d in setup: sum>0 <=> any>0
                unsigned long long bal = __ballot(mv[r4] > 0.f);
                if (lane == 0) pFlg[row] = bal ? 1u : 0u;
            } else if (lane == 0) {
                pFlg[row] = 0u;
            }
        }
        __syncthreads();                                   // B2

        // ---- mm3: hu = tanh(yc@Wu1+bu1), hr = tanh(yc@Wr1+br1), K=128 ----
        {
            half8 ah0 = *(const half8*)&pYCh[aOffH];
            half8 ah1 = *(const half8*)&pYCh[aOffH + 32];
            half8 ah2 = *(const half8*)&pYCh[aOffH + 64];
            half8 ah3 = *(const half8*)&pYCh[aOffH + 96];
            half8 al0 = *(const half8*)&pYCl[aOffH];
            half8 al1 = *(const half8*)&pYCl[aOffH + 32];
            half8 al2 = *(const half8*)&pYCl[aOffH + 64];
            half8 al3 = *(const half8*)&pYCl[aOffH + 96];
            floatx4 uhh = MFMA(ah3, wU1[3].h, MFMA(ah2, wU1[2].h,
                          MFMA(ah1, wU1[1].h, MFMA(ah0, wU1[0].h, z))));
            floatx4 uhl = MFMA(ah3, wU1[3].l, MFMA(ah2, wU1[2].l,
                          MFMA(ah1, wU1[1].l, MFMA(ah0, wU1[0].l, z))));
            floatx4 ulh = MFMA(al3, wU1[3].h, MFMA(al2, wU1[2].h,
                          MFMA(al1, wU1[1].h, MFMA(al0, wU1[0].h, z))));
            floatx4 rhh = MFMA(ah3, wR1[3].h, MFMA(ah2, wR1[2].h,
                          MFMA(ah1, wR1[1].h, MFMA(ah0, wR1[0].h, z))));
            floatx4 rhl = MFMA(ah3, wR1[3].l, MFMA(ah2, wR1[2].l,
                          MFMA(ah1, wR1[1].l, MFMA(ah0, wR1[0].l, z))));
            floatx4 rlh = MFMA(al3, wR1[3].h, MFMA(al2, wR1[2].h,
                          MFMA(al1, wR1[1].h, MFMA(al0, wR1[0].h, z))));
            floatx4 aU = uhh + (uhl + ulh);
            floatx4 aR = rhh + (rhl + rlh);
#pragma unroll
            for (int r = 0; r < 4; ++r) {
                float tu = tanhf_fast(aU[r] + bu1v);
                float tr = tanhf_fast(aR[r] + br1v);
                int idx = (quad * 4 + r) * 72 + ncol;
                _Float16 hu = (_Float16)tu, hr = (_Float16)tr;
                pHuh[idx] = hu; pHul[idx] = (_Float16)(tu - (float)hu);
                pHrh[idx] = hr; pHrl[idx] = (_Float16)(tr - (float)hr);
            }
        }
        __syncthreads();                                   // B3

        // ---- mm4: u = sig(hu@Wu2+bu2), r = sig(hr@Wr2+br2); cc = y1*r ----
        floatx4 uG;
        {
            half8 u0h = *(const half8*)&pHuh[aOff];
            half8 u0l = *(const half8*)&pHul[aOff];
            half8 u1h = *(const half8*)&pHuh[aOff + 32];
            half8 u1l = *(const half8*)&pHul[aOff + 32];
            floatx4 au = MFMA(u1h, wU2[1].h, MFMA(u0h, wU2[0].h, z))
                       + (MFMA(u1h, wU2[1].l, MFMA(u0h, wU2[0].l, z))
                        + MFMA(u1l, wU2[1].h, MFMA(u0l, wU2[0].h, z)));
            half8 r0h = *(const half8*)&pHrh[aOff];
            half8 r0l = *(const half8*)&pHrl[aOff];
            half8 r1h = *(const half8*)&pHrh[aOff + 32];
            half8 r1l = *(const half8*)&pHrl[aOff + 32];
            floatx4 ar = MFMA(r1h, wR2[1].h, MFMA(r0h, wR2[0].h, z))
                       + (MFMA(r1h, wR2[1].l, MFMA(r0h, wR2[0].l, z))
                        + MFMA(r1l, wR2[1].h, MFMA(r0l, wR2[0].h, z)));
#pragma unroll
            for (int r = 0; r < 4; ++r) {
                uG[r] = sigmoidf_fast(au[r] + bu2v);
                float rg = sigmoidf_fast(ar[r] + br2v);
                float cc = y1[r] * rg;
                _Float16 h = (_Float16)cc;
                int idx = (quad * 4 + r) * 136 + ncol;
                pCCh[idx] = h;
                pCCl[idx] = (_Float16)(cc - (float)h);
            }
        }
        __syncthreads();                                   // B4

        // ---- mm5: hn = tanh(cc @ Wn1 + bn1), K=128 ----
        {
            half8 ah0 = *(const half8*)&pCCh[aOffH];
            half8 ah1 = *(const half8*)&pCCh[aOffH + 32];
            half8 ah2 = *(const half8*)&pCCh[aOffH + 64];
            half8 ah3 = *(const half8*)&pCCh[aOffH + 96];
            half8 al0 = *(const half8*)&pCCl[aOffH];
            half8 al1 = *(const half8*)&pCCl[aOffH + 32];
            half8 al2 = *(const half8*)&pCCl[aOffH + 64];
            half8 al3 = *(const half8*)&pCCl[aOffH + 96];
            floatx4 nhh = MFMA(ah3, wN1[3].h, MFMA(ah2, wN1[2].h,
                          MFMA(ah1, wN1[1].h, MFMA(ah0, wN1[0].h, z))));
            floatx4 nhl = MFMA(ah3, wN1[3].l, MFMA(ah2, wN1[2].l,
                          MFMA(ah1, wN1[1].l, MFMA(ah0, wN1[0].l, z))));
            floatx4 nlh = MFMA(al3, wN1[3].h, MFMA(al2, wN1[2].h,
                          MFMA(al1, wN1[1].h, MFMA(al0, wN1[0].h, z))));
            floatx4 aN = nhh + (nhl + nlh);
#pragma unroll
            for (int r = 0; r < 4; ++r) {
                float t = tanhf_fast(aN[r] + bn1v);
                _Float16 h = (_Float16)t;
                int idx = (quad * 4 + r) * 72 + ncol;
                pHnh[idx] = h;
                pHnl[idx] = (_Float16)(t - (float)h);
            }
        }
        __syncthreads();                                   // B5

        // ---- mm6: ns = hn@Wn2 + bn2; blend; state update ----
        {
            half8 n0h = *(const half8*)&pHnh[aOff];
            half8 n0l = *(const half8*)&pHnl[aOff];
            half8 n1h = *(const half8*)&pHnh[aOff + 32];
            half8 n1l = *(const half8*)&pHnl[aOff + 32];
            floatx4 acc = MFMA(n1h, wN2[1].h, MFMA(n0h, wN2[0].h, z))
                        + (MFMA(n1h, wN2[1].l, MFMA(n0h, wN2[0].l, z))
                         + MFMA(n1l, wN2[1].h, MFMA(n0l, wN2[0].h, z)));
#pragma unroll
            for (int r = 0; r < 4; ++r) {
                float ns = acc[r] + bn2v;
                float ny = (1.0f - uG[r]) * ns + uG[r] * y1[r];
                unsigned ap = pFlg[quad * 4 + r];          // upd && m
                float nY = ap ? ny : y1[r];                // select: NaN-safe
                pc[r] = nY;
                int rr = quad * 4 + r;
                _Float16 h = (_Float16)nY;
                pYh[rr * 72 + ncol] = h;
                pYl[rr * 72 + ncol] = (_Float16)(nY - (float)h);
            }
        }
        __syncthreads();                                   // B6
    }

    // ---- epilogue ----
#pragma unroll
    for (int r = 0; r < 4; ++r) {
        int b = rowBase + quad * 4 + r;
        out[(size_t)b * 64 + ncol] = pc[r];
    }
    float* out1 = out + (size_t)4096 * 64;
    float* out2 = out1 + (size_t)4096 * 63;
#pragma unroll
    for (int r4 = 0; r4 < 4; ++r4) {
        int row = 4 * w4 + r4;
        int b = rowBase + row;
        if (lane < 63) {
            int t0 = tsteps[b * 64 + lane];
            int t1 = tsteps[b * 64 + lane + 1];
            int iv = t0 < 126 ? t0 : 126;
            out1[(size_t)b * 63 + lane] = pVol[row * 132 + iv + 1];
            out2[(size_t)b * 63 + lane] = (float)(t1 - t0);
        }
    }
}

extern "C" void kernel_launch(void* const* d_in, const int* in_sizes, int n_in,
                              void* d_out, int out_size, void* d_ws, size_t ws_size,
                              hipStream_t stream) {
    const float* data   = (const float*)d_in[0];
    const int*   tsteps = (const int*)  d_in[1];
    const float* Wu1 = (const float*)d_in[2];  const float* bu1 = (const float*)d_in[3];
    const float* Wu2 = (const float*)d_in[4];  const float* bu2 = (const float*)d_in[5];
    const float* Wr1 = (const float*)d_in[6];  const float* br1 = (const float*)d_in[7];
    const float* Wr2 = (const float*)d_in[8];  const float* br2 = (const float*)d_in[9];
    const float* Wn1 = (const float*)d_in[10]; const float* bn1 = (const float*)d_in[11];
    const float* Wn2 = (const float*)d_in[12]; const float* bn2 = (const float*)d_in[13];
    const float* Wo1 = (const float*)d_in[14]; const float* bo1 = (const float*)d_in[15];
    const float* Wo2 = (const float*)d_in[16]; const float* bo2 = (const float*)d_in[17];
    const float* Wd  = (const float*)d_in[18]; const float* bd  = (const float*)d_in[19];
    float* out = (float*)d_out;

    lobrm_fused<<<dim3(128), dim3(512), 0, stream>>>(
        data, tsteps, Wu1, bu1, Wu2, bu2, Wr1, br1, Wr2, br2,
        Wn1, bn1, Wn2, bn2, Wo1, bo1, Wo2, bo2, Wd, bd, out);
}

// Round 7
// 1015.603 us; speedup vs baseline: 1.7565x; 1.7541x over previous
//
#include <hip/hip_runtime.h>

// LOBRM fused recurrence on gfx950 — fp16 hi/lo split-precision MFMA, R7.
// R7 = R4's exact per-wave structure (256 thr, 200 VGPR, no spill) launched
// as 512 blocks of M=8-row tiles -> hardware co-schedules 2 independent
// blocks/CU = 2 waves/SIMD, filling each other's LDS/MFMA/barrier stalls.
// (R5/R6's 512-thread two-tile block was strangled by the backend's fixed
// 128-VGPR budget for 8-wave workgroups -> weight spill, 1781 us.)
// MFMA M-dim is half padding: pad rows are confined (MFMA rows independent),
// bounded (tanh/sigmoid), and never read by real outputs.

typedef __attribute__((ext_vector_type(8))) _Float16 half8;  // 8 fp16 = 4 VGPRs
typedef __attribute__((ext_vector_type(4))) float floatx4;   // MFMA C/D

#define MFMA(a, b, c) __builtin_amdgcn_mfma_f32_16x16x32_f16((a), (b), (c), 0, 0, 0)

__device__ __forceinline__ float tanhf_fast(float x) {
    float e = __builtin_exp2f(x * 2.8853900817779268f);  // e^{2x}
    return 1.0f - 2.0f / (e + 1.0f);                     // inf-safe: ->1 / -1
}
__device__ __forceinline__ float sigmoidf_fast(float x) {
    float e = __builtin_exp2f(x * -1.4426950408889634f); // e^{-x}
    return 1.0f / (1.0f + e);
}

struct W2 { half8 h, l; };

__global__ __launch_bounds__(256, 1)
void lobrm_fused(const float* __restrict__ data,   // (4096,64,100)
                 const int*   __restrict__ tsteps, // (4096,64)
                 const float* __restrict__ Wu1, const float* __restrict__ bu1,
                 const float* __restrict__ Wu2, const float* __restrict__ bu2,
                 const float* __restrict__ Wr1, const float* __restrict__ br1,
                 const float* __restrict__ Wr2, const float* __restrict__ br2,
                 const float* __restrict__ Wn1, const float* __restrict__ bn1,
                 const float* __restrict__ Wn2, const float* __restrict__ bn2,
                 const float* __restrict__ Wo1, const float* __restrict__ bo1,
                 const float* __restrict__ Wo2, const float* __restrict__ bo2,
                 const float* __restrict__ Wd,  const float* __restrict__ bd,
                 float* __restrict__ out)
{
    // fp16 hi/lo activation buffers (16 MFMA rows; rows 8..15 are pad).
    // Row strides 72/136 halfs: 16B-aligned rows for half8 (b128) access.
    __shared__ __align__(16) _Float16 sYh [16 * 72],  sYl [16 * 72];
    __shared__ __align__(16) _Float16 sTh [16 * 72],  sTl [16 * 72];
    __shared__ __align__(16) _Float16 sHuh[16 * 72],  sHul[16 * 72];
    __shared__ __align__(16) _Float16 sHrh[16 * 72],  sHrl[16 * 72];
    __shared__ __align__(16) _Float16 sHnh[16 * 72],  sHnl[16 * 72];
    __shared__ __align__(16) _Float16 sYCh[16 * 136], sYCl[16 * 136]; // [y1|feat|0]
    __shared__ __align__(16) _Float16 sCCh[16 * 136], sCCl[16 * 136]; // [y1*r|feat|0]
    __shared__ float    sVol[8 * 132];    // vol per real row per step
    __shared__ unsigned sFlg[16];         // apply = upd && m, per row

    const int tid   = threadIdx.x;
    const int lane  = tid & 63;
    const int wv    = tid >> 6;          // wave = N-slice
    const int col16 = lane & 15;
    const int quad  = lane >> 4;
    const int ncol  = wv * 16 + col16;   // output column 0..63
    const int rowBase = blockIdx.x * 8;  // tile's first batch row (8 rows)

    // ---- prologue: zero state + pad regions (pads must stay 0 forever) ----
    for (int x = tid; x < 16 * 72; x += 256) {
        sYh[x] = (_Float16)0.f; sYl[x] = (_Float16)0.f;
    }
    for (int x = tid; x < 16 * 136; x += 256) {
        sYCh[x] = (_Float16)0.f; sYCl[x] = (_Float16)0.f;
        sCCh[x] = (_Float16)0.f; sCCl[x] = (_Float16)0.f;
    }
    if (tid < 16) sFlg[tid] = 0u;
    const float bdv = bd[0];

    // ---- weight hi/lo B-fragments (this wave's 16-col slice) ----
    // B-frag for 16x16x32: lane holds B[k = kb*32 + quad*8 + j][n = ncol]
    auto loadW = [&](const float* W, int Kw, int kb) -> W2 {
        W2 f;
#pragma unroll
        for (int j = 0; j < 8; ++j) {
            int k = kb * 32 + quad * 8 + j;
            float v = (k < Kw) ? W[k * 64 + ncol] : 0.0f;
            _Float16 h = (_Float16)v;
            f.h[j] = h;
            f.l[j] = (_Float16)(v - (float)h);
        }
        return f;
    };
    W2 wO1[2], wO2[2], wU2[2], wR2[2], wN2[2], wU1[4], wR1[4], wN1[4];
#pragma unroll
    for (int kb = 0; kb < 2; ++kb) {
        wO1[kb] = loadW(Wo1, 64, kb);
        wO2[kb] = loadW(Wo2, 64, kb);
        wU2[kb] = loadW(Wu2, 64, kb);
        wR2[kb] = loadW(Wr2, 64, kb);
        wN2[kb] = loadW(Wn2, 64, kb);
    }
#pragma unroll
    for (int kb = 0; kb < 4; ++kb) {
        wU1[kb] = loadW(Wu1, 114, kb);
        wR1[kb] = loadW(Wr1, 114, kb);
        wN1[kb] = loadW(Wn1, 114, kb);
    }
    // vol B-frag (only wave 0 uses it): column 0 = Wd, cols 1..15 = 0. hi+lo.
    W2 vwd[2];
#pragma unroll
    for (int kb = 0; kb < 2; ++kb)
#pragma unroll
        for (int j = 0; j < 8; ++j) {
            int k = kb * 32 + quad * 8 + j;
            float v = (col16 == 0) ? Wd[k] : 0.0f;
            _Float16 h = (_Float16)v;
            vwd[kb].h[j] = h;
            vwd[kb].l[j] = (_Float16)(v - (float)h);
        }
    const float bo1v = bo1[ncol], bo2v = bo2[ncol];
    const float bu1v = bu1[ncol], bu2v = bu2[ncol];
    const float br1v = br1[ncol], br2v = br2[ncol];
    const float bn1v = bn1[ncol], bn2v = bn2[ncol];

    // ---- presence masks (dedup == reference's presence): wave wv owns
    // rows 2wv..2wv+1 for feat loading (8 real rows / 4 waves) ----
    unsigned long long mLo[2], mHi[2];
    const float* dPtr[2];
#pragma unroll
    for (int r2 = 0; r2 < 2; ++r2) {
        int b = rowBase + 2 * wv + r2;
        int v = tsteps[b * 64 + lane];
        unsigned long long lo = (v < 64) ? (1ull << v) : 0ull;
        unsigned long long hi = (v >= 64) ? (1ull << (v - 64)) : 0ull;
#pragma unroll
        for (int st = 1; st < 64; st <<= 1) {
            lo |= __shfl_xor(lo, st);
            hi |= __shfl_xor(hi, st);
        }
        mLo[r2] = lo; mHi[r2] = hi;
        dPtr[r2] = data + (size_t)b * 6400;
    }
    __syncthreads();

    floatx4 pc = {0.f, 0.f, 0.f, 0.f};   // fp32 state, C-layout slice
    const floatx4 z = {0.f, 0.f, 0.f, 0.f};

    const int aOff  = col16 * 72 + quad * 8;   // stride-72 A-frag base
    const int aOffH = col16 * 136 + quad * 8;  // stride-136 A-frag base

    for (int i = 0; i < 128; ++i) {
        // ---- A) issue feat global loads for this step (indep of chain) ----
        bool hasU[2];
        float fv[2], mv[2];
#pragma unroll
        for (int r2 = 0; r2 < 2; ++r2) {
            unsigned long long mm = (i < 64) ? (mLo[r2] >> i) : (mHi[r2] >> (i - 64));
            hasU[r2] = (mm & 1ull) != 0ull;
            fv[r2] = 0.f; mv[r2] = 0.f;
            if (hasU[r2]) {
                const float* dp = dPtr[r2];
                dPtr[r2] = dp + 100;
                if (lane < 50) { fv[r2] = dp[lane]; mv[r2] = dp[50 + lane]; }
            }
        }

        // ---- mm1: t = tanh(y @ Wo1 + bo1); wave 0: vol = y @ Wd + bd ----
        {
            half8 a0h = *(const half8*)&sYh[aOff];
            half8 a0l = *(const half8*)&sYl[aOff];
            half8 a1h = *(const half8*)&sYh[aOff + 32];
            half8 a1l = *(const half8*)&sYl[aOff + 32];
            floatx4 hh = MFMA(a1h, wO1[1].h, MFMA(a0h, wO1[0].h, z));
            floatx4 hl = MFMA(a1h, wO1[1].l, MFMA(a0h, wO1[0].l, z));
            floatx4 lh = MFMA(a1l, wO1[1].h, MFMA(a0l, wO1[0].h, z));
            if (wv == 0) {
                floatx4 vhh = MFMA(a1h, vwd[1].h, MFMA(a0h, vwd[0].h, z));
                floatx4 vhl = MFMA(a1h, vwd[1].l, MFMA(a0h, vwd[0].l, z));
                floatx4 vlh = MFMA(a1l, vwd[1].h, MFMA(a0l, vwd[0].h, z));
                floatx4 v = vhh + (vhl + vlh);
                if (col16 == 0) {
#pragma unroll
                    for (int r = 0; r < 4; ++r) {
                        int rr = quad * 4 + r;
                        if (rr < 8) sVol[rr * 132 + i] = v[r] + bdv;
                    }
                }
            }
            floatx4 acc = hh + (hl + lh);
#pragma unroll
            for (int r = 0; r < 4; ++r) {
                float t = tanhf_fast(acc[r] + bo1v);
                _Float16 h = (_Float16)t;
                int idx = (quad * 4 + r) * 72 + ncol;
                sTh[idx] = h;
                sTl[idx] = (_Float16)(t - (float)h);
            }
        }
        __syncthreads();                                   // B1

        // ---- mm2: y1 = y + t @ Wo2 + bo2 ----
        floatx4 y1;
        {
            half8 t0h = *(const half8*)&sTh[aOff];
            half8 t0l = *(const half8*)&sTl[aOff];
            half8 t1h = *(const half8*)&sTh[aOff + 32];
            half8 t1l = *(const half8*)&sTl[aOff + 32];
            floatx4 hh = MFMA(t1h, wO2[1].h, MFMA(t0h, wO2[0].h, z));
            floatx4 hl = MFMA(t1h, wO2[1].l, MFMA(t0h, wO2[0].l, z));
            floatx4 lh = MFMA(t1l, wO2[1].h, MFMA(t0l, wO2[0].h, z));
            floatx4 acc = hh + (hl + lh);
#pragma unroll
            for (int r = 0; r < 4; ++r) {
                y1[r] = pc[r] + acc[r] + bo2v;
                _Float16 h = (_Float16)y1[r];
                int idx = (quad * 4 + r) * 136 + ncol;
                sYCh[idx] = h;
                sYCl[idx] = (_Float16)(y1[r] - (float)h);
            }
        }

        // ---- C) feat commit (hi+lo) + flags (ballot; msk is abs()'d) ----
#pragma unroll
        for (int r2 = 0; r2 < 2; ++r2) {
            int row = 2 * wv + r2;
            if (hasU[r2]) {
                if (lane < 50) {
                    float f = fv[r2];
                    _Float16 h = (_Float16)f;
                    _Float16 l = (_Float16)(f - (float)h);
                    int idx = row * 136 + 64 + lane;
                    sYCh[idx] = h; sYCl[idx] = l;
                    sCCh[idx] = h; sCCl[idx] = l;
                }
                unsigned long long bal = __ballot(mv[r2] > 0.f);
                if (lane == 0) sFlg[row] = bal ? 1u : 0u;
            } else if (lane == 0) {
                sFlg[row] = 0u;
            }
        }
        __syncthreads();                                   // B2

        // ---- mm3: hu = tanh(yc@Wu1+bu1), hr = tanh(yc@Wr1+br1), K=128 ----
        {
            half8 ah0 = *(const half8*)&sYCh[aOffH];
            half8 ah1 = *(const half8*)&sYCh[aOffH + 32];
            half8 ah2 = *(const half8*)&sYCh[aOffH + 64];
            half8 ah3 = *(const half8*)&sYCh[aOffH + 96];
            half8 al0 = *(const half8*)&sYCl[aOffH];
            half8 al1 = *(const half8*)&sYCl[aOffH + 32];
            half8 al2 = *(const half8*)&sYCl[aOffH + 64];
            half8 al3 = *(const half8*)&sYCl[aOffH + 96];
            floatx4 uhh = MFMA(ah3, wU1[3].h, MFMA(ah2, wU1[2].h,
                          MFMA(ah1, wU1[1].h, MFMA(ah0, wU1[0].h, z))));
            floatx4 uhl = MFMA(ah3, wU1[3].l, MFMA(ah2, wU1[2].l,
                          MFMA(ah1, wU1[1].l, MFMA(ah0, wU1[0].l, z))));
            floatx4 ulh = MFMA(al3, wU1[3].h, MFMA(al2, wU1[2].h,
                          MFMA(al1, wU1[1].h, MFMA(al0, wU1[0].h, z))));
            floatx4 rhh = MFMA(ah3, wR1[3].h, MFMA(ah2, wR1[2].h,
                          MFMA(ah1, wR1[1].h, MFMA(ah0, wR1[0].h, z))));
            floatx4 rhl = MFMA(ah3, wR1[3].l, MFMA(ah2, wR1[2].l,
                          MFMA(ah1, wR1[1].l, MFMA(ah0, wR1[0].l, z))));
            floatx4 rlh = MFMA(al3, wR1[3].h, MFMA(al2, wR1[2].h,
                          MFMA(al1, wR1[1].h, MFMA(al0, wR1[0].h, z))));
            floatx4 aU = uhh + (uhl + ulh);
            floatx4 aR = rhh + (rhl + rlh);
#pragma unroll
            for (int r = 0; r < 4; ++r) {
                float tu = tanhf_fast(aU[r] + bu1v);
                float tr = tanhf_fast(aR[r] + br1v);
                int idx = (quad * 4 + r) * 72 + ncol;
                _Float16 hu = (_Float16)tu, hr = (_Float16)tr;
                sHuh[idx] = hu; sHul[idx] = (_Float16)(tu - (float)hu);
                sHrh[idx] = hr; sHrl[idx] = (_Float16)(tr - (float)hr);
            }
        }
        __syncthreads();                                   // B3

        // ---- mm4: u = sig(hu@Wu2+bu2), r = sig(hr@Wr2+br2); cc = y1*r ----
        floatx4 uG;
        {
            half8 u0h = *(const half8*)&sHuh[aOff];
            half8 u0l = *(const half8*)&sHul[aOff];
            half8 u1h = *(const half8*)&sHuh[aOff + 32];
            half8 u1l = *(const half8*)&sHul[aOff + 32];
            floatx4 au = MFMA(u1h, wU2[1].h, MFMA(u0h, wU2[0].h, z))
                       + (MFMA(u1h, wU2[1].l, MFMA(u0h, wU2[0].l, z))
                        + MFMA(u1l, wU2[1].h, MFMA(u0l, wU2[0].h, z)));
            half8 r0h = *(const half8*)&sHrh[aOff];
            half8 r0l = *(const half8*)&sHrl[aOff];
            half8 r1h = *(const half8*)&sHrh[aOff + 32];
            half8 r1l = *(const half8*)&sHrl[aOff + 32];
            floatx4 ar = MFMA(r1h, wR2[1].h, MFMA(r0h, wR2[0].h, z))
                       + (MFMA(r1h, wR2[1].l, MFMA(r0h, wR2[0].l, z))
                        + MFMA(r1l, wR2[1].h, MFMA(r0l, wR2[0].h, z)));
#pragma unroll
            for (int r = 0; r < 4; ++r) {
                uG[r] = sigmoidf_fast(au[r] + bu2v);
                float rg = sigmoidf_fast(ar[r] + br2v);
                float cc = y1[r] * rg;
                _Float16 h = (_Float16)cc;
                int idx = (quad * 4 + r) * 136 + ncol;
                sCCh[idx] = h;
                sCCl[idx] = (_Float16)(cc - (float)h);
            }
        }
        __syncthreads();                                   // B4

        // ---- mm5: hn = tanh(cc @ Wn1 + bn1), K=128 ----
        {
            half8 ah0 = *(const half8*)&sCCh[aOffH];
            half8 ah1 = *(const half8*)&sCCh[aOffH + 32];
            half8 ah2 = *(const half8*)&sCCh[aOffH + 64];
            half8 ah3 = *(const half8*)&sCCh[aOffH + 96];
            half8 al0 = *(const half8*)&sCCl[aOffH];
            half8 al1 = *(const half8*)&sCCl[aOffH + 32];
            half8 al2 = *(const half8*)&sCCl[aOffH + 64];
            half8 al3 = *(const half8*)&sCCl[aOffH + 96];
            floatx4 nhh = MFMA(ah3, wN1[3].h, MFMA(ah2, wN1[2].h,
                          MFMA(ah1, wN1[1].h, MFMA(ah0, wN1[0].h, z))));
            floatx4 nhl = MFMA(ah3, wN1[3].l, MFMA(ah2, wN1[2].l,
                          MFMA(ah1, wN1[1].l, MFMA(ah0, wN1[0].l, z))));
            floatx4 nlh = MFMA(al3, wN1[3].h, MFMA(al2, wN1[2].h,
                          MFMA(al1, wN1[1].h, MFMA(al0, wN1[0].h, z))));
            floatx4 aN = nhh + (nhl + nlh);
#pragma unroll
            for (int r = 0; r < 4; ++r) {
                float t = tanhf_fast(aN[r] + bn1v);
                _Float16 h = (_Float16)t;
                int idx = (quad * 4 + r) * 72 + ncol;
                sHnh[idx] = h;
                sHnl[idx] = (_Float16)(t - (float)h);
            }
        }
        __syncthreads();                                   // B5

        // ---- mm6: ns = hn@Wn2 + bn2; blend; state update ----
        {
            half8 n0h = *(const half8*)&sHnh[aOff];
            half8 n0l = *(const half8*)&sHnl[aOff];
            half8 n1h = *(const half8*)&sHnh[aOff + 32];
            half8 n1l = *(const half8*)&sHnl[aOff + 32];
            floatx4 acc = MFMA(n1h, wN2[1].h, MFMA(n0h, wN2[0].h, z))
                        + (MFMA(n1h, wN2[1].l, MFMA(n0h, wN2[0].l, z))
                         + MFMA(n1l, wN2[1].h, MFMA(n0l, wN2[0].h, z)));
#pragma unroll
            for (int r = 0; r < 4; ++r) {
                float ns = acc[r] + bn2v;
                float ny = (1.0f - uG[r]) * ns + uG[r] * y1[r];
                unsigned ap = sFlg[quad * 4 + r];          // upd && m
                float nY = ap ? ny : y1[r];                // select: NaN-safe
                pc[r] = nY;
                int rr = quad * 4 + r;
                _Float16 h = (_Float16)nY;
                sYh[rr * 72 + ncol] = h;
                sYl[rr * 72 + ncol] = (_Float16)(nY - (float)h);
            }
        }
        __syncthreads();                                   // B6
    }

    // ---- epilogue (8 real rows) ----
#pragma unroll
    for (int r = 0; r < 4; ++r) {
        int rr = quad * 4 + r;
        if (rr < 8) out[(size_t)(rowBase + rr) * 64 + ncol] = pc[r];
    }
    float* out1 = out + (size_t)4096 * 64;
    float* out2 = out1 + (size_t)4096 * 63;
#pragma unroll
    for (int r2 = 0; r2 < 2; ++r2) {
        int row = 2 * wv + r2;
        int b = rowBase + row;
        if (lane < 63) {
            int t0 = tsteps[b * 64 + lane];
            int t1 = tsteps[b * 64 + lane + 1];
            int iv = t0 < 126 ? t0 : 126;
            out1[(size_t)b * 63 + lane] = sVol[row * 132 + iv + 1];
            out2[(size_t)b * 63 + lane] = (float)(t1 - t0);
        }
    }
}

extern "C" void kernel_launch(void* const* d_in, const int* in_sizes, int n_in,
                              void* d_out, int out_size, void* d_ws, size_t ws_size,
                              hipStream_t stream) {
    const float* data   = (const float*)d_in[0];
    const int*   tsteps = (const int*)  d_in[1];
    const float* Wu1 = (const float*)d_in[2];  const float* bu1 = (const float*)d_in[3];
    const float* Wu2 = (const float*)d_in[4];  const float* bu2 = (const float*)d_in[5];
    const float* Wr1 = (const float*)d_in[6];  const float* br1 = (const float*)d_in[7];
    const float* Wr2 = (const float*)d_in[8];  const float* br2 = (const float*)d_in[9];
    const float* Wn1 = (const float*)d_in[10]; const float* bn1 = (const float*)d_in[11];
    const float* Wn2 = (const float*)d_in[12]; const float* bn2 = (const float*)d_in[13];
    const float* Wo1 = (const float*)d_in[14]; const float* bo1 = (const float*)d_in[15];
    const float* Wo2 = (const float*)d_in[16]; const float* bo2 = (const float*)d_in[17];
    const float* Wd  = (const float*)d_in[18]; const float* bd  = (const float*)d_in[19];
    float* out = (float*)d_out;

    lobrm_fused<<<dim3(512), dim3(256), 0, stream>>>(
        data, tsteps, Wu1, bu1, Wu2, bu2, Wr1, br1, Wr2, br2,
        Wn1, bn1, Wn2, bn2, Wo1, bo1, Wo2, bo2, Wd, bd, out);
}

// Round 8
// 599.492 us; speedup vs baseline: 2.9758x; 1.6941x over previous
//
#include <hip/hip_runtime.h>

// LOBRM fused recurrence on gfx950 — fp16 hi/lo split-precision MFMA, R8.
// R8 = R4 frame (256 blocks x 256 thr, M=16 tile, weights in VGPRs,
// 1 wave/SIMD — occupancy is register-structural per R5-R7 evidence) with
// serial-path shaving:
//  - feat global loads prefetched ONE STEP AHEAD (compiler's vmcnt(0) drain
//    before each s_barrier exposed their latency at B1; now they get the
//    whole mm1 segment to land)
//  - MFMA hh-chains init with bias splat (C/D cols are lane-uniform here)
//  - __ballot flag (msk half of data is abs()'d: sum>0 <=> any>0)
//  - vol = hh term only (leaf output, error ~0.03 << 0.705)
//  - sT aliased for Hn (disjoint lifetimes)

typedef __attribute__((ext_vector_type(8))) _Float16 half8;  // 8 fp16 = 4 VGPRs
typedef __attribute__((ext_vector_type(4))) float floatx4;   // MFMA C/D

#define MFMA(a, b, c) __builtin_amdgcn_mfma_f32_16x16x32_f16((a), (b), (c), 0, 0, 0)

__device__ __forceinline__ float tanhf_fast(float x) {
    float e = __builtin_exp2f(x * 2.8853900817779268f);  // e^{2x}
    return 1.0f - 2.0f / (e + 1.0f);                     // inf-safe: ->1 / -1
}
__device__ __forceinline__ float sigmoidf_fast(float x) {
    float e = __builtin_exp2f(x * -1.4426950408889634f); // e^{-x}
    return 1.0f / (1.0f + e);
}

struct W2 { half8 h, l; };

__global__ __launch_bounds__(256, 1)
void lobrm_fused(const float* __restrict__ data,   // (4096,64,100)
                 const int*   __restrict__ tsteps, // (4096,64)
                 const float* __restrict__ Wu1, const float* __restrict__ bu1,
                 const float* __restrict__ Wu2, const float* __restrict__ bu2,
                 const float* __restrict__ Wr1, const float* __restrict__ br1,
                 const float* __restrict__ Wr2, const float* __restrict__ br2,
                 const float* __restrict__ Wn1, const float* __restrict__ bn1,
                 const float* __restrict__ Wn2, const float* __restrict__ bn2,
                 const float* __restrict__ Wo1, const float* __restrict__ bo1,
                 const float* __restrict__ Wo2, const float* __restrict__ bo2,
                 const float* __restrict__ Wd,  const float* __restrict__ bd,
                 float* __restrict__ out)
{
    // fp16 hi/lo activation buffers. Row strides 72/136 halfs: 16B-aligned.
    // sTh/sTl double as Hn buffers (T: mm1->mm2, Hn: mm5->mm6; disjoint).
    __shared__ __align__(16) _Float16 sYh [16 * 72],  sYl [16 * 72];
    __shared__ __align__(16) _Float16 sTh [16 * 72],  sTl [16 * 72];
    __shared__ __align__(16) _Float16 sHuh[16 * 72],  sHul[16 * 72];
    __shared__ __align__(16) _Float16 sHrh[16 * 72],  sHrl[16 * 72];
    __shared__ __align__(16) _Float16 sYCh[16 * 136], sYCl[16 * 136]; // [y1|feat|0]
    __shared__ __align__(16) _Float16 sCCh[16 * 136], sCCl[16 * 136]; // [y1*r|feat|0]
    __shared__ float    sVol[16 * 132];   // vol per row per step
    __shared__ unsigned sFlg[16];         // apply = upd && m, per row

    const int tid   = threadIdx.x;
    const int lane  = tid & 63;
    const int wv    = tid >> 6;          // wave = N-slice
    const int col16 = lane & 15;
    const int quad  = lane >> 4;
    const int ncol  = wv * 16 + col16;   // output column 0..63
    const int rowBase = blockIdx.x * 16;

    // ---- prologue: zero state + pad regions (pads must stay 0 forever) ----
    for (int x = tid; x < 16 * 72; x += 256) {
        sYh[x] = (_Float16)0.f; sYl[x] = (_Float16)0.f;
    }
    for (int x = tid; x < 16 * 136; x += 256) {
        sYCh[x] = (_Float16)0.f; sYCl[x] = (_Float16)0.f;
        sCCh[x] = (_Float16)0.f; sCCl[x] = (_Float16)0.f;
    }
    const float bdv = bd[0];

    // ---- weight hi/lo B-fragments (this wave's 16-col slice) ----
    // B-frag for 16x16x32: lane holds B[k = kb*32 + quad*8 + j][n = ncol]
    auto loadW = [&](const float* W, int Kw, int kb) -> W2 {
        W2 f;
#pragma unroll
        for (int j = 0; j < 8; ++j) {
            int k = kb * 32 + quad * 8 + j;
            float v = (k < Kw) ? W[k * 64 + ncol] : 0.0f;
            _Float16 h = (_Float16)v;
            f.h[j] = h;
            f.l[j] = (_Float16)(v - (float)h);
        }
        return f;
    };
    W2 wO1[2], wO2[2], wU2[2], wR2[2], wN2[2], wU1[4], wR1[4], wN1[4];
#pragma unroll
    for (int kb = 0; kb < 2; ++kb) {
        wO1[kb] = loadW(Wo1, 64, kb);
        wO2[kb] = loadW(Wo2, 64, kb);
        wU2[kb] = loadW(Wu2, 64, kb);
        wR2[kb] = loadW(Wr2, 64, kb);
        wN2[kb] = loadW(Wn2, 64, kb);
    }
#pragma unroll
    for (int kb = 0; kb < 4; ++kb) {
        wU1[kb] = loadW(Wu1, 114, kb);
        wR1[kb] = loadW(Wr1, 114, kb);
        wN1[kb] = loadW(Wn1, 114, kb);
    }
    // vol B-frag (only wave 0 uses it): column 0 = Wd, cols 1..15 = 0.
    // hi-only: vol is a leaf output, lo terms contribute ~0.03 abs.
    half8 vwd[2];
#pragma unroll
    for (int kb = 0; kb < 2; ++kb)
#pragma unroll
        for (int j = 0; j < 8; ++j) {
            int k = kb * 32 + quad * 8 + j;
            vwd[kb][j] = (_Float16)((col16 == 0) ? Wd[k] : 0.0f);
        }
    const float bo1v = bo1[ncol], bo2v = bo2[ncol];
    const float bu1v = bu1[ncol], bu2v = bu2[ncol];
    const float br1v = br1[ncol], br2v = br2[ncol];
    const float bn1v = bn1[ncol], bn2v = bn2[ncol];

    // ---- presence masks (dedup == reference's presence): wave wv owns
    // rows 4wv..4wv+3 for feat loading ----
    unsigned long long mLo[4], mHi[4];
    const float* dPtr[4];
#pragma unroll
    for (int r4 = 0; r4 < 4; ++r4) {
        int b = rowBase + 4 * wv + r4;
        int v = tsteps[b * 64 + lane];
        unsigned long long lo = (v < 64) ? (1ull << v) : 0ull;
        unsigned long long hi = (v >= 64) ? (1ull << (v - 64)) : 0ull;
#pragma unroll
        for (int st = 1; st < 64; st <<= 1) {
            lo |= __shfl_xor(lo, st);
            hi |= __shfl_xor(hi, st);
        }
        mLo[r4] = lo; mHi[r4] = hi;
        dPtr[r4] = data + (size_t)b * 6400;
    }
    __syncthreads();

    floatx4 pc = {0.f, 0.f, 0.f, 0.f};   // fp32 state, C-layout slice
    const floatx4 z = {0.f, 0.f, 0.f, 0.f};

    const int aOff  = col16 * 72 + quad * 8;   // stride-72 A-frag base
    const int aOffH = col16 * 136 + quad * 8;  // stride-136 A-frag base

    // ---- prefetch step 0's feat loads ----
    bool hasU[4];
    float fv[4], mv[4];
#pragma unroll
    for (int r4 = 0; r4 < 4; ++r4) {
        hasU[r4] = (mLo[r4] & 1ull) != 0ull;
        fv[r4] = 0.f; mv[r4] = 0.f;
        if (hasU[r4]) {
            const float* dp = dPtr[r4];
            dPtr[r4] = dp + 100;
            if (lane < 50) { fv[r4] = dp[lane]; mv[r4] = dp[50 + lane]; }
        }
    }

    for (int i = 0; i < 128; ++i) {
        // ---- A) issue NEXT step's feat loads (consumed next iteration;
        //      the vmcnt(0) drain at B1 gives them the mm1 segment to land) ----
        const int ip = i + 1;
        bool hasN[4];
        float fN[4], mN[4];
#pragma unroll
        for (int r4 = 0; r4 < 4; ++r4) {
            unsigned long long mm =
                (ip < 64) ? (mLo[r4] >> ip)
                          : ((ip < 128) ? (mHi[r4] >> (ip - 64)) : 0ull);
            hasN[r4] = (mm & 1ull) != 0ull;
            fN[r4] = 0.f; mN[r4] = 0.f;
            if (hasN[r4]) {
                const float* dp = dPtr[r4];
                dPtr[r4] = dp + 100;
                if (lane < 50) { fN[r4] = dp[lane]; mN[r4] = dp[50 + lane]; }
            }
        }

        // ---- mm1: t = tanh(y @ Wo1 + bo1); wave 0: vol = y @ Wd + bd ----
        {
            half8 a0h = *(const half8*)&sYh[aOff];
            half8 a0l = *(const half8*)&sYl[aOff];
            half8 a1h = *(const half8*)&sYh[aOff + 32];
            half8 a1l = *(const half8*)&sYl[aOff + 32];
            floatx4 cb = {bo1v, bo1v, bo1v, bo1v};
            floatx4 hh = MFMA(a1h, wO1[1].h, MFMA(a0h, wO1[0].h, cb));
            floatx4 hl = MFMA(a1h, wO1[1].l, MFMA(a0h, wO1[0].l, z));
            floatx4 lh = MFMA(a1l, wO1[1].h, MFMA(a0l, wO1[0].h, z));
            if (wv == 0) {
                floatx4 v = MFMA(a1h, vwd[1], MFMA(a0h, vwd[0], z));
                if (col16 == 0) {
#pragma unroll
                    for (int r = 0; r < 4; ++r)
                        sVol[(quad * 4 + r) * 132 + i] = v[r] + bdv;
                }
            }
            floatx4 acc = hh + (hl + lh);
#pragma unroll
            for (int r = 0; r < 4; ++r) {
                float t = tanhf_fast(acc[r]);
                _Float16 h = (_Float16)t;
                int idx = (quad * 4 + r) * 72 + ncol;
                sTh[idx] = h;
                sTl[idx] = (_Float16)(t - (float)h);
            }
        }
        __syncthreads();                                   // B1

        // ---- mm2: y1 = y + t @ Wo2 + bo2 ----
        floatx4 y1;
        {
            half8 t0h = *(const half8*)&sTh[aOff];
            half8 t0l = *(const half8*)&sTl[aOff];
            half8 t1h = *(const half8*)&sTh[aOff + 32];
            half8 t1l = *(const half8*)&sTl[aOff + 32];
            floatx4 cb = {bo2v, bo2v, bo2v, bo2v};
            floatx4 hh = MFMA(t1h, wO2[1].h, MFMA(t0h, wO2[0].h, cb));
            floatx4 hl = MFMA(t1h, wO2[1].l, MFMA(t0h, wO2[0].l, z));
            floatx4 lh = MFMA(t1l, wO2[1].h, MFMA(t0l, wO2[0].h, z));
            floatx4 acc = hh + (hl + lh);
#pragma unroll
            for (int r = 0; r < 4; ++r) {
                y1[r] = pc[r] + acc[r];
                _Float16 h = (_Float16)y1[r];
                int idx = (quad * 4 + r) * 136 + ncol;
                sYCh[idx] = h;
                sYCl[idx] = (_Float16)(y1[r] - (float)h);
            }
        }

        // ---- C) feat commit (hi+lo, prefetched last iter) + ballot flags ----
#pragma unroll
        for (int r4 = 0; r4 < 4; ++r4) {
            int row = 4 * wv + r4;
            if (hasU[r4]) {
                if (lane < 50) {
                    float f = fv[r4];
                    _Float16 h = (_Float16)f;
                    _Float16 l = (_Float16)(f - (float)h);
                    int idx = row * 136 + 64 + lane;
                    sYCh[idx] = h; sYCl[idx] = l;
                    sCCh[idx] = h; sCCl[idx] = l;
                }
                unsigned long long bal = __ballot(mv[r4] > 0.f);
                if (lane == 0) sFlg[row] = bal ? 1u : 0u;
            } else if (lane == 0) {
                sFlg[row] = 0u;
            }
        }
        __syncthreads();                                   // B2

        // ---- mm3: hu = tanh(yc@Wu1+bu1), hr = tanh(yc@Wr1+br1), K=128 ----
        {
            half8 ah0 = *(const half8*)&sYCh[aOffH];
            half8 ah1 = *(const half8*)&sYCh[aOffH + 32];
            half8 ah2 = *(const half8*)&sYCh[aOffH + 64];
            half8 ah3 = *(const half8*)&sYCh[aOffH + 96];
            half8 al0 = *(const half8*)&sYCl[aOffH];
            half8 al1 = *(const half8*)&sYCl[aOffH + 32];
            half8 al2 = *(const half8*)&sYCl[aOffH + 64];
            half8 al3 = *(const half8*)&sYCl[aOffH + 96];
            floatx4 cu = {bu1v, bu1v, bu1v, bu1v};
            floatx4 cr = {br1v, br1v, br1v, br1v};
            floatx4 uhh = MFMA(ah3, wU1[3].h, MFMA(ah2, wU1[2].h,
                          MFMA(ah1, wU1[1].h, MFMA(ah0, wU1[0].h, cu))));
            floatx4 uhl = MFMA(ah3, wU1[3].l, MFMA(ah2, wU1[2].l,
                          MFMA(ah1, wU1[1].l, MFMA(ah0, wU1[0].l, z))));
            floatx4 ulh = MFMA(al3, wU1[3].h, MFMA(al2, wU1[2].h,
                          MFMA(al1, wU1[1].h, MFMA(al0, wU1[0].h, z))));
            floatx4 rhh = MFMA(ah3, wR1[3].h, MFMA(ah2, wR1[2].h,
                          MFMA(ah1, wR1[1].h, MFMA(ah0, wR1[0].h, cr))));
            floatx4 rhl = MFMA(ah3, wR1[3].l, MFMA(ah2, wR1[2].l,
                          MFMA(ah1, wR1[1].l, MFMA(ah0, wR1[0].l, z))));
            floatx4 rlh = MFMA(al3, wR1[3].h, MFMA(al2, wR1[2].h,
                          MFMA(al1, wR1[1].h, MFMA(al0, wR1[0].h, z))));
            floatx4 aU = uhh + (uhl + ulh);
            floatx4 aR = rhh + (rhl + rlh);
#pragma unroll
            for (int r = 0; r < 4; ++r) {
                float tu = tanhf_fast(aU[r]);
                float tr = tanhf_fast(aR[r]);
                int idx = (quad * 4 + r) * 72 + ncol;
                _Float16 hu = (_Float16)tu, hr = (_Float16)tr;
                sHuh[idx] = hu; sHul[idx] = (_Float16)(tu - (float)hu);
                sHrh[idx] = hr; sHrl[idx] = (_Float16)(tr - (float)hr);
            }
        }
        __syncthreads();                                   // B3

        // ---- mm4: u = sig(hu@Wu2+bu2), r = sig(hr@Wr2+br2); cc = y1*r ----
        floatx4 uG;
        {
            half8 u0h = *(const half8*)&sHuh[aOff];
            half8 u0l = *(const half8*)&sHul[aOff];
            half8 u1h = *(const half8*)&sHuh[aOff + 32];
            half8 u1l = *(const half8*)&sHul[aOff + 32];
            floatx4 cu = {bu2v, bu2v, bu2v, bu2v};
            floatx4 cr = {br2v, br2v, br2v, br2v};
            floatx4 au = MFMA(u1h, wU2[1].h, MFMA(u0h, wU2[0].h, cu))
                       + (MFMA(u1h, wU2[1].l, MFMA(u0h, wU2[0].l, z))
                        + MFMA(u1l, wU2[1].h, MFMA(u0l, wU2[0].h, z)));
            half8 r0h = *(const half8*)&sHrh[aOff];
            half8 r0l = *(const half8*)&sHrl[aOff];
            half8 r1h = *(const half8*)&sHrh[aOff + 32];
            half8 r1l = *(const half8*)&sHrl[aOff + 32];
            floatx4 ar = MFMA(r1h, wR2[1].h, MFMA(r0h, wR2[0].h, cr))
                       + (MFMA(r1h, wR2[1].l, MFMA(r0h, wR2[0].l, z))
                        + MFMA(r1l, wR2[1].h, MFMA(r0l, wR2[0].h, z)));
#pragma unroll
            for (int r = 0; r < 4; ++r) {
                uG[r] = sigmoidf_fast(au[r]);
                float rg = sigmoidf_fast(ar[r]);
                float cc = y1[r] * rg;
                _Float16 h = (_Float16)cc;
                int idx = (quad * 4 + r) * 136 + ncol;
                sCCh[idx] = h;
                sCCl[idx] = (_Float16)(cc - (float)h);
            }
        }
        __syncthreads();                                   // B4

        // ---- mm5: hn = tanh(cc @ Wn1 + bn1), K=128 (into sT alias) ----
        {
            half8 ah0 = *(const half8*)&sCCh[aOffH];
            half8 ah1 = *(const half8*)&sCCh[aOffH + 32];
            half8 ah2 = *(const half8*)&sCCh[aOffH + 64];
            half8 ah3 = *(const half8*)&sCCh[aOffH + 96];
            half8 al0 = *(const half8*)&sCCl[aOffH];
            half8 al1 = *(const half8*)&sCCl[aOffH + 32];
            half8 al2 = *(const half8*)&sCCl[aOffH + 64];
            half8 al3 = *(const half8*)&sCCl[aOffH + 96];
            floatx4 cn = {bn1v, bn1v, bn1v, bn1v};
            floatx4 nhh = MFMA(ah3, wN1[3].h, MFMA(ah2, wN1[2].h,
                          MFMA(ah1, wN1[1].h, MFMA(ah0, wN1[0].h, cn))));
            floatx4 nhl = MFMA(ah3, wN1[3].l, MFMA(ah2, wN1[2].l,
                          MFMA(ah1, wN1[1].l, MFMA(ah0, wN1[0].l, z))));
            floatx4 nlh = MFMA(al3, wN1[3].h, MFMA(al2, wN1[2].h,
                          MFMA(al1, wN1[1].h, MFMA(al0, wN1[0].h, z))));
            floatx4 aN = nhh + (nhl + nlh);
#pragma unroll
            for (int r = 0; r < 4; ++r) {
                float t = tanhf_fast(aN[r]);
                _Float16 h = (_Float16)t;
                int idx = (quad * 4 + r) * 72 + ncol;
                sTh[idx] = h;
                sTl[idx] = (_Float16)(t - (float)h);
            }
        }
        __syncthreads();                                   // B5

        // ---- mm6: ns = hn@Wn2 + bn2; blend; state update ----
        {
            half8 n0h = *(const half8*)&sTh[aOff];
            half8 n0l = *(const half8*)&sTl[aOff];
            half8 n1h = *(const half8*)&sTh[aOff + 32];
            half8 n1l = *(const half8*)&sTl[aOff + 32];
            floatx4 cn = {bn2v, bn2v, bn2v, bn2v};
            floatx4 acc = MFMA(n1h, wN2[1].h, MFMA(n0h, wN2[0].h, cn))
                        + (MFMA(n1h, wN2[1].l, MFMA(n0h, wN2[0].l, z))
                         + MFMA(n1l, wN2[1].h, MFMA(n0l, wN2[0].h, z)));
#pragma unroll
            for (int r = 0; r < 4; ++r) {
                float ns = acc[r];
                float ny = (1.0f - uG[r]) * ns + uG[r] * y1[r];
                unsigned ap = sFlg[quad * 4 + r];          // upd && m
                float nY = ap ? ny : y1[r];                // select: NaN-safe
                pc[r] = nY;
                int rr = quad * 4 + r;
                _Float16 h = (_Float16)nY;
                sYh[rr * 72 + ncol] = h;
                sYl[rr * 72 + ncol] = (_Float16)(nY - (float)h);
            }
        }
        __syncthreads();                                   // B6

        // ---- rotate prefetched feat ----
#pragma unroll
        for (int r4 = 0; r4 < 4; ++r4) {
            hasU[r4] = hasN[r4];
            fv[r4] = fN[r4];
            mv[r4] = mN[r4];
        }
    }

    // ---- epilogue ----
#pragma unroll
    for (int r = 0; r < 4; ++r) {
        int b = rowBase + quad * 4 + r;
        out[(size_t)b * 64 + ncol] = pc[r];
    }
    float* out1 = out + (size_t)4096 * 64;
    float* out2 = out1 + (size_t)4096 * 63;
#pragma unroll
    for (int r4 = 0; r4 < 4; ++r4) {
        int row = 4 * wv + r4;
        int b = rowBase + row;
        if (lane < 63) {
            int t0 = tsteps[b * 64 + lane];
            int t1 = tsteps[b * 64 + lane + 1];
            int iv = t0 < 126 ? t0 : 126;
            out1[(size_t)b * 63 + lane] = sVol[row * 132 + iv + 1];
            out2[(size_t)b * 63 + lane] = (float)(t1 - t0);
        }
    }
}

extern "C" void kernel_launch(void* const* d_in, const int* in_sizes, int n_in,
                              void* d_out, int out_size, void* d_ws, size_t ws_size,
                              hipStream_t stream) {
    const float* data   = (const float*)d_in[0];
    const int*   tsteps = (const int*)  d_in[1];
    const float* Wu1 = (const float*)d_in[2];  const float* bu1 = (const float*)d_in[3];
    const float* Wu2 = (const float*)d_in[4];  const float* bu2 = (const float*)d_in[5];
    const float* Wr1 = (const float*)d_in[6];  const float* br1 = (const float*)d_in[7];
    const float* Wr2 = (const float*)d_in[8];  const float* br2 = (const float*)d_in[9];
    const float* Wn1 = (const float*)d_in[10]; const float* bn1 = (const float*)d_in[11];
    const float* Wn2 = (const float*)d_in[12]; const float* bn2 = (const float*)d_in[13];
    const float* Wo1 = (const float*)d_in[14]; const float* bo1 = (const float*)d_in[15];
    const float* Wo2 = (const float*)d_in[16]; const float* bo2 = (const float*)d_in[17];
    const float* Wd  = (const float*)d_in[18]; const float* bd  = (const float*)d_in[19];
    float* out = (float*)d_out;

    lobrm_fused<<<dim3(256), dim3(256), 0, stream>>>(
        data, tsteps, Wu1, bu1, Wu2, bu2, Wr1, br1, Wr2, br2,
        Wn1, bn1, Wn2, bn2, Wo1, bo1, Wo2, bo2, Wd, bd, out);
}